// Round 7
// baseline (735.842 us; speedup 1.0000x reference)
//
#include <hip/hip_runtime.h>

// Problem constants (mirrors reference)
#define NI    32              // batch
#define HH    1024
#define WW    1024
#define BHW   16              // pool window
#define BS    14              // block stride
#define NBH   73              // block count h
#define NBW   73              // block count w
#define NCHUNK (NI * NBH)     // 2336 block-rows
#define TOTAL  (NI * NBH * NBW) // 170528

#define VALID 0x40000000      // bit30: clear in 0xAAAAAAAA poison AND in zeroed mem

__device__ __forceinline__ float4 max4(float4 a, float4 b) {
    return make_float4(fmaxf(a.x, b.x), fmaxf(a.y, b.y),
                       fmaxf(a.z, b.z), fmaxf(a.w, b.w));
}

// ---------------------------------------------------------------------------
// Single fused kernel: pool (w/ probabilistic early exit) + decoupled-lookback
// prefix + stable scatter + -1 slack fill. One workgroup per (n,by) chunk.
//
// Pool: stream rows in pairs with running colmax; after each pair a
// conservative ballot test (3 fully-interior 4-col bits per window, no false
// positives) proves all 73 windows > 0.9 and exits early (~4.8 of 16 rows on
// uniform data). No-exit path (P~1e-7/chunk) falls through to the exact
// colmax + horizontal pass — bit-identical semantics.
//
// Lookback: publish (VALID|count) with release/agent atomic; poll lower-ID
// chunks with acquire/agent atomics to build the exclusive prefix e. Blocks
// only ever wait on lower IDs (rocPRIM-style forward progress). Counts are
// deterministic per input, so even a stale-but-valid value from a previous
// replay is the correct value — idempotent across graph replays.
//
// Output coverage: actives write rows [0, grand_total) via e+prefix; slack
// regions S_incl(i) = (i+1)*NBW - (e+c) tile [grand_total, TOTAL) disjointly
// -> every output row written exactly once per call (d_out is re-poisoned).
__global__ __launch_bounds__(256, 8) void fused_kernel(const float* __restrict__ mask,
                                                       int* __restrict__ pub,
                                                       int* __restrict__ out) {
    const int chunk = blockIdx.x;         // n*NBH + by
    const int n  = chunk / NBH;
    const int by = chunk % NBH;
    const int tid  = threadIdx.x;
    const int lane = tid & 63;
    const int wave = tid >> 6;

    __shared__ float colmax[WW];
    __shared__ unsigned long long wb[2][4];
    __shared__ int sdone[2][4];
    __shared__ unsigned long long sm0, sm1;
    __shared__ int wsum[4];

    // ---------------- pool phase ----------------
    const int r0 = by * BS - 1;           // padded window start (pad=1)
    const int rs = max(r0, 0);            // only by==0 clips; top edge never does
    const int nr = (by > 0) ? 16 : 15;    // valid rows in window
    const float* p = mask + (size_t)n * HH * WW + (size_t)rs * WW + tid * 4;

    float4 m = make_float4(-1e30f, -1e30f, -1e30f, -1e30f);
    bool done = false;

    for (int k = 0; k < 8 && !done; ++k) {
        const int buf = k & 1;
        const int r1 = 2 * k, r2 = 2 * k + 1;
        m = max4(m, *(const float4*)(p + (size_t)r1 * WW));
        if (r2 < nr)                      // block-uniform predicate
            m = max4(m, *(const float4*)(p + (size_t)r2 * WW));

        const float mm = fmaxf(fmaxf(m.x, m.y), fmaxf(m.z, m.w));
        const unsigned long long bal = __ballot(mm > 0.9f);
        if (lane == 0) wb[buf][wave] = bal;
        __syncthreads();

        bool whit = true;
        if (tid < NBW) {
            const int c0 = tid * BS;
            const int lo = (c0 + 2) >> 2;         // first 4-col bit fully inside
            const int w0 = lo >> 6, sh = lo & 63;
            unsigned long long bits = wb[buf][w0] >> sh;
            if (w0 < 3 && sh) bits |= wb[buf][w0 + 1] << (64 - sh);
            whit = (bits & 7ull) != 0ull;         // 3 interior bits
        }
        const unsigned long long miss = __ballot(!whit);  // tid>=73 -> whit=true
        if (lane == 0) sdone[buf][wave] = (miss == 0ull);
        __syncthreads();
        done = (sdone[buf][0] & sdone[buf][1] & sdone[buf][2] & sdone[buf][3]) != 0;
        // next iter writes buf^1 -> no third barrier needed
    }

    if (done) {                           // exact: every window proved > 0.9
        if (tid == 0) {
            sm0 = ~0ull;
            sm1 = (1ull << (NBW - 64)) - 1ull;
            __hip_atomic_store(&pub[chunk], VALID | NBW,
                               __ATOMIC_RELEASE, __HIP_MEMORY_SCOPE_AGENT);
        }
    } else {
        // exact fallback (all valid rows accumulated in m)
        const int c4 = tid * 4;
        colmax[c4 + 0] = m.x;
        colmax[c4 + 1] = m.y;
        colmax[c4 + 2] = m.z;
        colmax[c4 + 3] = m.w;
        __syncthreads();

        int f = 0;
        if (tid < NBW) {
            const int c0 = tid * BS - 1;
            float mx = colmax[max(c0, 0)];    // dc=0 clamped; dc>=1 always >= 0
            #pragma unroll
            for (int dc = 1; dc < BHW; ++dc) mx = fmaxf(mx, colmax[c0 + dc]);
            f = (mx > 0.9f) ? 1 : 0;
        }
        const unsigned long long b = __ballot(f);
        if (wave == 0 && lane == 0) sm0 = b;  // bits for bx 0..63
        if (wave == 1 && lane == 0) sm1 = b;  // bits for bx 64..72
        __syncthreads();
        if (tid == 0) {
            const int c = __popcll(sm0) + __popcll(sm1);
            __hip_atomic_store(&pub[chunk], VALID | c,
                               __ATOMIC_RELEASE, __HIP_MEMORY_SCOPE_AGENT);
        }
    }
    __syncthreads();                      // sm0/sm1 visible to all

    // ---------------- lookback prefix ----------------
    int partial = 0;
    for (int i = tid; i < chunk; i += 256) {
        int v = __hip_atomic_load(&pub[i], __ATOMIC_ACQUIRE, __HIP_MEMORY_SCOPE_AGENT);
        while (!(v & VALID)) {
            __builtin_amdgcn_s_sleep(1);
            v = __hip_atomic_load(&pub[i], __ATOMIC_ACQUIRE, __HIP_MEMORY_SCOPE_AGENT);
        }
        partial += v & 0x3FF;
    }
    #pragma unroll
    for (int off = 32; off > 0; off >>= 1) partial += __shfl_down(partial, off, 64);
    if (lane == 0) wsum[wave] = partial;
    __syncthreads();
    const int e = wsum[0] + wsum[1] + wsum[2] + wsum[3];
    const int c = __popcll(sm0) + __popcll(sm1);

    // ---------------- stable scatter ----------------
    if (tid < NBW) {
        int f, prefix;
        if (wave == 0) {                  // bx 0..63 (wave-uniform branch)
            f = (int)((sm0 >> tid) & 1ull);
            prefix = __popcll(sm0 & ((1ull << tid) - 1ull));
        } else {                          // bx 64..72
            const int t = tid - 64;
            f = (int)((sm1 >> t) & 1ull);
            prefix = __popcll(sm0) + __popcll(sm1 & ((1ull << t) - 1ull));
        }
        if (f) {
            const int pos = e + prefix;
            out[3 * pos + 0] = n;
            out[3 * pos + 1] = by;
            out[3 * pos + 2] = tid;
        }
    }

    // ---------------- -1 slack fill ----------------
    const int slack = NBW - c;            // 0 when all 73 windows active
    if (slack > 0) {
        const int s_incl = (chunk + 1) * NBW - (e + c);
        const int base3 = 3 * (TOTAL - s_incl);
        const int n3 = 3 * slack;
        for (int i = tid; i < n3; i += 256) out[base3 + i] = -1;
    }
}

// ---------------------------------------------------------------------------
extern "C" void kernel_launch(void* const* d_in, const int* in_sizes, int n_in,
                              void* d_out, int out_size, void* d_ws, size_t ws_size,
                              hipStream_t stream) {
    const float* mask = (const float*)d_in[0];
    int* out = (int*)d_out;
    int* pub = (int*)d_ws;                // 2336 x int publication slots

    fused_kernel<<<NCHUNK, 256, 0, stream>>>(mask, pub, out);
}

// Round 8
// 177.928 us; speedup vs baseline: 4.1356x; 4.1356x over previous
//
#include <hip/hip_runtime.h>

// Problem constants (mirrors reference)
#define NI    32              // batch
#define HH    1024
#define WW    1024
#define BHW   16              // pool window
#define BS    14              // block stride
#define NBH   73              // block count h
#define NBW   73              // block count w
#define NCHUNK (NI * NBH)     // 2336 block-rows
#define TOTAL  (NI * NBH * NBW) // 170528

struct umask2 { unsigned long long x, y; };

__device__ __forceinline__ float4 max4(float4 a, float4 b) {
    return make_float4(fmaxf(a.x, b.x), fmaxf(a.y, b.y),
                       fmaxf(a.z, b.z), fmaxf(a.w, b.w));
}

// ---------------------------------------------------------------------------
// Kernel 1: one workgroup per (n, by) block-row, probabilistic early exit.
// Flags are booleans of a monotone max: once every window provably contains
// an element > 0.9, remaining rows are irrelevant. Stream rows in pairs with
// running colmax; after each pair, per-lane "colmax4 > 0.9" ballots give a
// 256-bit map (1 bit = 4 cols). Window bx (cols [14bx-1, 14bx+14]) tests only
// its 3 fully-interior bits -> a set bit proves the window (no false
// positives); exit emits the exact all-ones mask/count=73. Uniform data exits
// after ~4-6 of 16 rows. No-exit path (P~1e-7/chunk) falls through to the
// exact colmax + horizontal pass — bit-identical semantics.
// NOTE (R7 lesson): do NOT fuse scan via agent-scope acquire/release lookback
// — cache-maintenance per atomic collapses BW on non-coherent-XCD gfx950
// (617 us vs 178 us total).
__global__ __launch_bounds__(256, 8) void pool_kernel(const float* __restrict__ mask,
                                                      umask2* __restrict__ masks,
                                                      int* __restrict__ counts) {
    const int chunk = blockIdx.x;         // n*NBH + by
    const int n  = chunk / NBH;
    const int by = chunk % NBH;
    const int tid  = threadIdx.x;
    const int lane = tid & 63;
    const int wave = tid >> 6;

    __shared__ float colmax[WW];
    __shared__ unsigned long long wb[2][4];
    __shared__ int sdone[2][4];
    __shared__ unsigned long long sm0, sm1;

    const int r0 = by * BS - 1;           // padded window start (pad=1)
    const int rs = max(r0, 0);            // only by==0 clips; top edge never does
    const int nr = (by > 0) ? 16 : 15;    // valid rows in window
    const float* p = mask + (size_t)n * HH * WW + (size_t)rs * WW + tid * 4;

    float4 m = make_float4(-1e30f, -1e30f, -1e30f, -1e30f);
    bool done = false;

    for (int k = 0; k < 8 && !done; ++k) {
        const int buf = k & 1;
        const int r1 = 2 * k, r2 = 2 * k + 1;
        m = max4(m, *(const float4*)(p + (size_t)r1 * WW));
        if (r2 < nr)                      // block-uniform predicate
            m = max4(m, *(const float4*)(p + (size_t)r2 * WW));

        const float mm = fmaxf(fmaxf(m.x, m.y), fmaxf(m.z, m.w));
        const unsigned long long bal = __ballot(mm > 0.9f);
        if (lane == 0) wb[buf][wave] = bal;
        __syncthreads();

        bool whit = true;
        if (tid < NBW) {
            const int c0 = tid * BS;
            const int lo = (c0 + 2) >> 2;         // first 4-col bit fully inside
            const int w0 = lo >> 6, sh = lo & 63;
            unsigned long long bits = wb[buf][w0] >> sh;
            if (w0 < 3 && sh) bits |= wb[buf][w0 + 1] << (64 - sh);
            whit = (bits & 7ull) != 0ull;         // exactly 3 interior bits
        }
        const unsigned long long miss = __ballot(!whit);  // tid>=73 -> whit=true
        if (lane == 0) sdone[buf][wave] = (miss == 0ull);
        __syncthreads();
        done = (sdone[buf][0] & sdone[buf][1] & sdone[buf][2] & sdone[buf][3]) != 0;
        // next iteration writes buf^1 -> no third barrier needed
    }

    if (done) {                           // exact: every window proved > 0.9
        if (tid == 0) {
            umask2 mmk; mmk.x = ~0ull; mmk.y = (1ull << (NBW - 64)) - 1ull;
            masks[chunk] = mmk;
            counts[chunk] = NBW;
        }
        return;                           // block-uniform
    }

    // exact fallback (all valid rows accumulated in m)
    const int c = tid * 4;
    colmax[c + 0] = m.x;
    colmax[c + 1] = m.y;
    colmax[c + 2] = m.z;
    colmax[c + 3] = m.w;
    __syncthreads();

    int f = 0;
    if (tid < NBW) {
        const int c0 = tid * BS - 1;
        float mx = colmax[max(c0, 0)];    // dc=0 clamped; dc>=1 always >= 0
        #pragma unroll
        for (int dc = 1; dc < BHW; ++dc) mx = fmaxf(mx, colmax[c0 + dc]);
        f = (mx > 0.9f) ? 1 : 0;
    }
    const unsigned long long b = __ballot(f);
    if (wave == 0 && lane == 0) sm0 = b;  // bits for bx 0..63
    if (wave == 1 && lane == 0) sm1 = b;  // bits for bx 64..72
    __syncthreads();
    if (tid == 0) {
        umask2 mm2; mm2.x = sm0; mm2.y = sm1;
        masks[chunk] = mm2;
        counts[chunk] = __popcll(sm0) + __popcll(sm1);
    }
}

// ---------------------------------------------------------------------------
// Kernel 2: fused exclusive-scan + stable scatter + -1 tail fill.
// Block recomputes its global offset by summing counts[0..chunk-1] (L2-hot),
// scatters (n, by, bx) triples, then fills its disjoint slack region:
//   S_incl(i) = (i+1)*NBW - (e_i + c_i); block i fills
//   rows [TOTAL - S_incl, TOTAL - S_incl + (NBW - c_i))  — exact tiling of
//   [grand_total, TOTAL); every output row written exactly once.
__global__ __launch_bounds__(128) void scatter_kernel(const umask2* __restrict__ masks,
                                                      const int* __restrict__ counts,
                                                      int* __restrict__ out) {
    const int chunk = blockIdx.x;
    const int n  = chunk / NBH;
    const int by = chunk % NBH;
    const int tid  = threadIdx.x;
    const int lane = tid & 63;
    const int wave = tid >> 6;

    __shared__ int wsum[2];

    // global exclusive prefix of counts
    int partial = 0;
    for (int i = tid; i < chunk; i += 128) partial += counts[i];
    #pragma unroll
    for (int off = 32; off > 0; off >>= 1) partial += __shfl_down(partial, off, 64);
    if (lane == 0) wsum[wave] = partial;

    const umask2 m = masks[chunk];        // broadcast load, L2-hot
    __syncthreads();
    const int e = wsum[0] + wsum[1];
    const int c = __popcll(m.x) + __popcll(m.y);

    // stable scatter of active triples
    if (tid < NBW) {
        int f, prefix;
        if (wave == 0) {                  // bx 0..63 (wave-uniform branch)
            f = (int)((m.x >> tid) & 1ull);
            prefix = __popcll(m.x & ((1ull << tid) - 1ull));
        } else {                          // bx 64..72
            const int t = tid - 64;
            f = (int)((m.y >> t) & 1ull);
            prefix = __popcll(m.x) + __popcll(m.y & ((1ull << t) - 1ull));
        }
        if (f) {
            const int pos = e + prefix;
            out[3 * pos + 0] = n;
            out[3 * pos + 1] = by;
            out[3 * pos + 2] = tid;
        }
    }

    // -1 slack fill (zero iterations when all 73 blocks in this row are active)
    const int slack = NBW - c;
    if (slack > 0) {
        const int s_incl = (chunk + 1) * NBW - (e + c);
        const int base3 = 3 * (TOTAL - s_incl);
        const int n3 = 3 * slack;
        for (int i = tid; i < n3; i += 128) out[base3 + i] = -1;
    }
}

// ---------------------------------------------------------------------------
extern "C" void kernel_launch(void* const* d_in, const int* in_sizes, int n_in,
                              void* d_out, int out_size, void* d_ws, size_t ws_size,
                              hipStream_t stream) {
    const float* mask = (const float*)d_in[0];
    int* out = (int*)d_out;

    // workspace layout: [masks: 2336 x 16B][counts: 2336 x 4B]
    umask2* masks = (umask2*)d_ws;
    int* counts = (int*)(masks + NCHUNK);

    pool_kernel<<<NCHUNK, 256, 0, stream>>>(mask, masks, counts);
    scatter_kernel<<<NCHUNK, 128, 0, stream>>>(masks, counts, out);
}